// Round 3
// baseline (67.904 us; speedup 1.0000x reference)
//
#include <hip/hip_runtime.h>
#include <math.h>

// Batched dynamic bicycle model, 10 substeps h=0.01f.
// R2: latency/issue-bound (VALUBusy 41%, hbm 33%). Cut critical path:
//  - 2 rows/thread as ext_vector_type(2) -> v_pk_*_f32 packed math
//  - replace per-substep __sincosf with initial sincos + 2nd-order
//    incremental rotation (err <= d^3/6 ~ 4e-4/step, tol 0.104)

typedef float v2f __attribute__((ext_vector_type(2)));

__device__ __forceinline__ float med3(float x, float lo, float hi) {
    return __builtin_amdgcn_fmed3f(x, lo, hi);
}
__device__ __forceinline__ v2f vfma(v2f a, v2f b, v2f c) {
    return __builtin_elementwise_fma(a, b, c);
}

__global__ __launch_bounds__(256) void bicycle_kernel(
    const float* __restrict__ state_in,   // (B,9)
    const float* __restrict__ action_in,  // (B,2)
    float* __restrict__ out)              // (B,9)
{
    constexpr float MAX_STEER = (float)(30.0 * 3.141592653589793 / 180.0); // 0.5235988
    constexpr float V_EFF_MIN = (float)(20.0 / 3.6);                       // 5.5555553
    constexpr float FY_F_MAX  = (float)(0.9 * 1500.0 * 9.81 * (1.6 / 2.8)); // 7567.7143
    constexpr float FY_R_MAX  = (float)(0.9 * 1500.0 * 9.81 * (1.2 / 2.8)); // 5675.7857

    constexpr int RPB = 512;                  // rows per block (2 per thread)
    __shared__ float smem[RPB * 9];           // 18432 B

    const int tid = threadIdx.x;
    const size_t rowBase = (size_t)blockIdx.x * RPB;

    // ---- coalesced float4 global -> LDS ----
    const float4* g4 = (const float4*)(state_in + rowBase * 9);
    float4* l4 = (float4*)smem;
    l4[tid]        = g4[tid];
    l4[tid + 256]  = g4[tid + 256];
    l4[tid + 512]  = g4[tid + 512];
    l4[tid + 768]  = g4[tid + 768];
    if (tid < 128) l4[tid + 1024] = g4[tid + 1024];

    // ---- action: directly coalesced float2 per row ----
    const float2* a2 = (const float2*)action_in + rowBase;
    float2 act0 = a2[tid];
    float2 act1 = a2[tid + 256];
    __syncthreads();

    // ---- gather 2 rows into packed v2f state ----
    const int rb0 = tid * 9;
    const int rb1 = (tid + 256) * 9;
    v2f x, y, psi, v, a, delta, beta, r;
    x     = (v2f){smem[rb0 + 0], smem[rb1 + 0]};
    y     = (v2f){smem[rb0 + 1], smem[rb1 + 1]};
    psi   = (v2f){smem[rb0 + 2], smem[rb1 + 2]};
    v     = (v2f){fmaxf(smem[rb0 + 3], 0.0f), fmaxf(smem[rb1 + 3], 0.0f)};
    a     = (v2f){smem[rb0 + 4], smem[rb1 + 4]};
    delta = (v2f){med3(smem[rb0 + 5], -MAX_STEER, MAX_STEER),
                  med3(smem[rb1 + 5], -MAX_STEER, MAX_STEER)};
    beta  = (v2f){smem[rb0 + 6], smem[rb1 + 6]};
    r     = (v2f){smem[rb0 + 7], smem[rb1 + 7]};
    v2f a_ref = (v2f){med3(act0.x, -6.0f, 3.0f), med3(act1.x, -6.0f, 3.0f)};
    v2f d_ref = (v2f){med3(act0.y, -MAX_STEER, MAX_STEER), med3(act1.y, -MAX_STEER, MAX_STEER)};

    // initial heading direction (only accurate sincos; then incremental rotation)
    v2f cs, sn;
    {
        float s0, c0, s1, c1;
        __sincosf(psi.x + beta.x, &s0, &c0);
        __sincosf(psi.y + beta.y, &s1, &c1);
        cs = (v2f){c0, c1};
        sn = (v2f){s0, s1};
    }

#pragma unroll
    for (int k = 0; k < 10; ++k) {
        v2f v_eff = {fmaxf(v.x, V_EFF_MIN), fmaxf(v.y, V_EFF_MIN)};
        v2f inv_v = {__builtin_amdgcn_rcpf(v_eff.x), __builtin_amdgcn_rcpf(v_eff.y)};
        v2f t = r * inv_v;
        v2f alpha_f = vfma((v2f)(1.2f), t, beta) - delta;
        v2f alpha_r = vfma((v2f)(-1.6f), t, beta);
        v2f Ff_raw = alpha_f * -80000.0f;
        v2f Fr_raw = alpha_r * -80000.0f;
        v2f F_yf = {med3(Ff_raw.x, -FY_F_MAX, FY_F_MAX), med3(Ff_raw.y, -FY_F_MAX, FY_F_MAX)};
        v2f F_yr = {med3(Fr_raw.x, -FY_R_MAX, FY_R_MAX), med3(Fr_raw.y, -FY_R_MAX, FY_R_MAX)};
        v2f beta_dot = vfma(F_yf + F_yr, inv_v * (1.0f / 1500.0f), -r);
        v2f r_dot = vfma((v2f)(1.2f), F_yf, F_yr * -1.6f) * (1.0f / 2250.0f);

        // x,y from CURRENT heading
        v2f vh = v * 0.01f;
        x = vfma(vh, cs, x);
        y = vfma(vh, sn, y);

        // incremental rotation of (cs,sn) by d = (r + beta_dot)*h
        v2f d  = (r + beta_dot) * 0.01f;
        v2f cd = vfma(d * d, (v2f)(-0.5f), (v2f)(1.0f));
        v2f cs_n = vfma(cs, cd, -(sn * d));
        v2f sn_n = vfma(sn, cd, cs * d);

        v2f v_new = vfma(a, (v2f)(0.01f), v);
        v_new = (v2f){fmaxf(v_new.x, 0.0f), fmaxf(v_new.y, 0.0f)};
        psi  = vfma(r, (v2f)(0.01f), psi);
        a    = vfma(a_ref - a, (v2f)(0.1f), a);
        v2f dlt = vfma(d_ref - delta, (v2f)(0.1f), delta);
        delta = (v2f){med3(dlt.x, -MAX_STEER, MAX_STEER), med3(dlt.y, -MAX_STEER, MAX_STEER)};
        beta = vfma(beta_dot, (v2f)(0.01f), beta);
        r    = vfma(r_dot, (v2f)(0.01f), r);
        v = v_new;
        cs = cs_n;
        sn = sn_n;
    }

    // ---- write rows back to LDS, then coalesced float4 store ----
    smem[rb0 + 0] = x.x;     smem[rb1 + 0] = x.y;
    smem[rb0 + 1] = y.x;     smem[rb1 + 1] = y.y;
    smem[rb0 + 2] = psi.x;   smem[rb1 + 2] = psi.y;
    smem[rb0 + 3] = v.x;     smem[rb1 + 3] = v.y;
    smem[rb0 + 4] = a.x;     smem[rb1 + 4] = a.y;
    smem[rb0 + 5] = delta.x; smem[rb1 + 5] = delta.y;
    smem[rb0 + 6] = beta.x;  smem[rb1 + 6] = beta.y;
    smem[rb0 + 7] = r.x;     smem[rb1 + 7] = r.y;
    smem[rb0 + 8] = d_ref.x; smem[rb1 + 8] = d_ref.y;
    __syncthreads();

    float4* o4 = (float4*)(out + rowBase * 9);
    o4[tid]       = l4[tid];
    o4[tid + 256] = l4[tid + 256];
    o4[tid + 512] = l4[tid + 512];
    o4[tid + 768] = l4[tid + 768];
    if (tid < 128) o4[tid + 1024] = l4[tid + 1024];
}

extern "C" void kernel_launch(void* const* d_in, const int* in_sizes, int n_in,
                              void* d_out, int out_size, void* d_ws, size_t ws_size,
                              hipStream_t stream) {
    const float* state  = (const float*)d_in[0];
    const float* action = (const float*)d_in[1];
    float* out = (float*)d_out;
    const int rows = in_sizes[0] / 9;        // 4194304
    const int grid = rows / 512;             // 8192 blocks, exact
    bicycle_kernel<<<grid, 256, 0, stream>>>(state, action, out);
}

// Round 4
// 57.216 us; speedup vs baseline: 1.1868x; 1.1868x over previous
//
#include <hip/hip_runtime.h>
#include <math.h>

// Batched dynamic bicycle model, 10 substeps h=0.01f.
// R3: latency/phase-bound (VALU 28%, HBM 57% true). This round:
//  - 4 rows/thread (2 packed v2f chains) -> 2x per-wave ILP + 2x vmem in flight
//  - nontemporal output stores (nt): don't evict the L3-resident input with
//    the 151MB output stream (FETCH_SIZE was 90MB of pure L3 eviction refetch)

typedef float v2f __attribute__((ext_vector_type(2)));
typedef float f4  __attribute__((ext_vector_type(4)));

__device__ __forceinline__ float med3(float x, float lo, float hi) {
    return __builtin_amdgcn_fmed3f(x, lo, hi);
}
__device__ __forceinline__ v2f vfma(v2f a, v2f b, v2f c) {
    return __builtin_elementwise_fma(a, b, c);
}

__global__ __launch_bounds__(256) void bicycle_kernel(
    const float* __restrict__ state_in,   // (B,9)
    const float* __restrict__ action_in,  // (B,2)
    float* __restrict__ out)              // (B,9)
{
    constexpr float MAX_STEER = (float)(30.0 * 3.141592653589793 / 180.0); // 0.5235988
    constexpr float V_EFF_MIN = (float)(20.0 / 3.6);                       // 5.5555553
    constexpr float FY_F_MAX  = (float)(0.9 * 1500.0 * 9.81 * (1.6 / 2.8)); // 7567.7143
    constexpr float FY_R_MAX  = (float)(0.9 * 1500.0 * 9.81 * (1.2 / 2.8)); // 5675.7857

    constexpr int RPB = 1024;                 // rows per block (4 per thread)
    __shared__ float smem[RPB * 9];           // 36864 B -> 4 blocks/CU

    const int tid = threadIdx.x;
    const size_t rowBase = (size_t)blockIdx.x * RPB;

    // ---- coalesced float4 global -> LDS (2304 float4 per block, 9/thread) ----
    const f4* g4 = (const f4*)(state_in + rowBase * 9);
    f4* l4 = (f4*)smem;
#pragma unroll
    for (int i = 0; i < 9; ++i) l4[tid + 256 * i] = g4[tid + 256 * i];

    // ---- action: directly coalesced float2 per row ----
    const float2* a2 = (const float2*)action_in + rowBase;
    float2 act[4];
#pragma unroll
    for (int j = 0; j < 4; ++j) act[j] = a2[tid + 256 * j];
    __syncthreads();

    // ---- gather 4 rows into 2 packed v2f chains ----
    v2f x[2], y[2], psi[2], v[2], a[2], delta[2], beta[2], r[2];
    v2f a_ref[2], d_ref[2], cs[2], sn[2];
#pragma unroll
    for (int p = 0; p < 2; ++p) {
        const int rbA = (tid + (2 * p + 0) * 256) * 9;
        const int rbB = (tid + (2 * p + 1) * 256) * 9;
        x[p]     = (v2f){smem[rbA + 0], smem[rbB + 0]};
        y[p]     = (v2f){smem[rbA + 1], smem[rbB + 1]};
        psi[p]   = (v2f){smem[rbA + 2], smem[rbB + 2]};
        v[p]     = (v2f){fmaxf(smem[rbA + 3], 0.0f), fmaxf(smem[rbB + 3], 0.0f)};
        a[p]     = (v2f){smem[rbA + 4], smem[rbB + 4]};
        delta[p] = (v2f){med3(smem[rbA + 5], -MAX_STEER, MAX_STEER),
                         med3(smem[rbB + 5], -MAX_STEER, MAX_STEER)};
        beta[p]  = (v2f){smem[rbA + 6], smem[rbB + 6]};
        r[p]     = (v2f){smem[rbA + 7], smem[rbB + 7]};
        a_ref[p] = (v2f){med3(act[2 * p].x, -6.0f, 3.0f),
                         med3(act[2 * p + 1].x, -6.0f, 3.0f)};
        d_ref[p] = (v2f){med3(act[2 * p].y, -MAX_STEER, MAX_STEER),
                         med3(act[2 * p + 1].y, -MAX_STEER, MAX_STEER)};
        float s0, c0, s1, c1;
        __sincosf(psi[p].x + beta[p].x, &s0, &c0);
        __sincosf(psi[p].y + beta[p].y, &s1, &c1);
        cs[p] = (v2f){c0, c1};
        sn[p] = (v2f){s0, s1};
    }

#pragma unroll
    for (int k = 0; k < 10; ++k) {
#pragma unroll
        for (int p = 0; p < 2; ++p) {
            v2f v_eff = {fmaxf(v[p].x, V_EFF_MIN), fmaxf(v[p].y, V_EFF_MIN)};
            v2f inv_v = {__builtin_amdgcn_rcpf(v_eff.x), __builtin_amdgcn_rcpf(v_eff.y)};
            v2f t = r[p] * inv_v;
            v2f alpha_f = vfma((v2f)(1.2f), t, beta[p]) - delta[p];
            v2f alpha_r = vfma((v2f)(-1.6f), t, beta[p]);
            v2f Ff_raw = alpha_f * -80000.0f;
            v2f Fr_raw = alpha_r * -80000.0f;
            v2f F_yf = {med3(Ff_raw.x, -FY_F_MAX, FY_F_MAX), med3(Ff_raw.y, -FY_F_MAX, FY_F_MAX)};
            v2f F_yr = {med3(Fr_raw.x, -FY_R_MAX, FY_R_MAX), med3(Fr_raw.y, -FY_R_MAX, FY_R_MAX)};
            v2f beta_dot = vfma(F_yf + F_yr, inv_v * (1.0f / 1500.0f), -r[p]);
            v2f r_dot = vfma((v2f)(1.2f), F_yf, F_yr * -1.6f) * (1.0f / 2250.0f);

            v2f vh = v[p] * 0.01f;
            x[p] = vfma(vh, cs[p], x[p]);
            y[p] = vfma(vh, sn[p], y[p]);

            // incremental rotation of heading by d = (r + beta_dot)*h
            v2f d  = (r[p] + beta_dot) * 0.01f;
            v2f cd = vfma(d * d, (v2f)(-0.5f), (v2f)(1.0f));
            v2f cs_n = vfma(cs[p], cd, -(sn[p] * d));
            v2f sn_n = vfma(sn[p], cd, cs[p] * d);

            v2f v_new = vfma(a[p], (v2f)(0.01f), v[p]);
            v_new = (v2f){fmaxf(v_new.x, 0.0f), fmaxf(v_new.y, 0.0f)};
            psi[p]  = vfma(r[p], (v2f)(0.01f), psi[p]);
            a[p]    = vfma(a_ref[p] - a[p], (v2f)(0.1f), a[p]);
            v2f dlt = vfma(d_ref[p] - delta[p], (v2f)(0.1f), delta[p]);
            delta[p] = (v2f){med3(dlt.x, -MAX_STEER, MAX_STEER), med3(dlt.y, -MAX_STEER, MAX_STEER)};
            beta[p] = vfma(beta_dot, (v2f)(0.01f), beta[p]);
            r[p]    = vfma(r_dot, (v2f)(0.01f), r[p]);
            v[p] = v_new;
            cs[p] = cs_n;
            sn[p] = sn_n;
        }
    }

    // ---- write rows back to LDS ----
    __syncthreads();   // ensure all input reads done before overwrite (same buffer)
#pragma unroll
    for (int p = 0; p < 2; ++p) {
        const int rbA = (tid + (2 * p + 0) * 256) * 9;
        const int rbB = (tid + (2 * p + 1) * 256) * 9;
        smem[rbA + 0] = x[p].x;     smem[rbB + 0] = x[p].y;
        smem[rbA + 1] = y[p].x;     smem[rbB + 1] = y[p].y;
        smem[rbA + 2] = psi[p].x;   smem[rbB + 2] = psi[p].y;
        smem[rbA + 3] = v[p].x;     smem[rbB + 3] = v[p].y;
        smem[rbA + 4] = a[p].x;     smem[rbB + 4] = a[p].y;
        smem[rbA + 5] = delta[p].x; smem[rbB + 5] = delta[p].y;
        smem[rbA + 6] = beta[p].x;  smem[rbB + 6] = beta[p].y;
        smem[rbA + 7] = r[p].x;     smem[rbB + 7] = r[p].y;
        smem[rbA + 8] = d_ref[p].x; smem[rbB + 8] = d_ref[p].y;
    }
    __syncthreads();

    // ---- coalesced nontemporal float4 store (don't evict L3-resident input) ----
    f4* o4 = (f4*)(out + rowBase * 9);
#pragma unroll
    for (int i = 0; i < 9; ++i)
        __builtin_nontemporal_store(l4[tid + 256 * i], &o4[tid + 256 * i]);
}

extern "C" void kernel_launch(void* const* d_in, const int* in_sizes, int n_in,
                              void* d_out, int out_size, void* d_ws, size_t ws_size,
                              hipStream_t stream) {
    const float* state  = (const float*)d_in[0];
    const float* action = (const float*)d_in[1];
    float* out = (float*)d_out;
    const int rows = in_sizes[0] / 9;        // 4194304
    const int grid = rows / 1024;            // 4096 blocks, exact
    bicycle_kernel<<<grid, 256, 0, stream>>>(state, action, out);
}

// Round 5
// 56.312 us; speedup vs baseline: 1.2059x; 1.0161x over previous
//
#include <hip/hip_runtime.h>
#include <math.h>

// Batched dynamic bicycle model, 10 substeps h=0.01f.
// R4: ILP (4 rows/thread) helped but 36KB LDS halved occupancy (36%).
// This round: half-size LDS (18.4KB -> 8 blocks/CU) with two-phase staging;
// all global loads issued up-front (T14 split: half B parked in regs),
// self-owned LDS rows per thread so only transpose phases need barriers.

typedef float v2f __attribute__((ext_vector_type(2)));
typedef float f4  __attribute__((ext_vector_type(4)));

__device__ __forceinline__ float med3(float x, float lo, float hi) {
    return __builtin_amdgcn_fmed3f(x, lo, hi);
}
__device__ __forceinline__ v2f vfma2(v2f a, v2f b, v2f c) {
    return __builtin_elementwise_fma(a, b, c);
}

__global__ __launch_bounds__(256) void bicycle_kernel(
    const float* __restrict__ state_in,   // (B,9)
    const float* __restrict__ action_in,  // (B,2)
    float* __restrict__ out)              // (B,9)
{
    constexpr float MAX_STEER = (float)(30.0 * 3.141592653589793 / 180.0); // 0.5235988
    constexpr float V_EFF_MIN = (float)(20.0 / 3.6);                       // 5.5555553
    constexpr float FY_F_MAX  = (float)(0.9 * 1500.0 * 9.81 * (1.6 / 2.8)); // 7567.7143
    constexpr float FY_R_MAX  = (float)(0.9 * 1500.0 * 9.81 * (1.2 / 2.8)); // 5675.7857

    __shared__ float smem[512 * 9];           // 18432 B -> LDS cap 8 blocks/CU

    const int tid = threadIdx.x;
    const size_t rowBase = (size_t)blockIdx.x * 1024;

    const f4* gA = (const f4*)(state_in + rowBase * 9);          // rows [0,512)
    const f4* gB = (const f4*)(state_in + (rowBase + 512) * 9);  // rows [512,1024)
    f4* l4 = (f4*)smem;

    // ---- issue ALL global loads up-front (14 vmem in flight) ----
    f4 rA[4], rB[4], rA4, rB4;
#pragma unroll
    for (int i = 0; i < 4; ++i) rA[i] = gA[tid + 256 * i];
    if (tid < 128) rA4 = gA[tid + 1024];
#pragma unroll
    for (int i = 0; i < 4; ++i) rB[i] = gB[tid + 256 * i];
    if (tid < 128) rB4 = gB[tid + 1024];

    const float2* a2 = (const float2*)action_in + rowBase;
    float2 act[4];
#pragma unroll
    for (int j = 0; j < 4; ++j) act[j] = a2[tid + 256 * j];

    // ---- stage half A into LDS ----
#pragma unroll
    for (int i = 0; i < 4; ++i) l4[tid + 256 * i] = rA[i];
    if (tid < 128) l4[tid + 1024] = rA4;
    __syncthreads();

    v2f x[2], y[2], psi[2], v[2], a[2], delta[2], beta[2], r[2];
    v2f a_ref[2], d_ref[2], cs[2], sn[2];

    // Each thread's chains both live in LDS rows (tid, tid+256): self-owned,
    // so chain read/write needs no barrier; only float4 transposes do.
#define READ_CHAIN(P, ACT0, ACT1) do {                                         \
        const int rb0 = tid * 9;                                               \
        const int rb1 = (tid + 256) * 9;                                       \
        x[P]     = (v2f){smem[rb0 + 0], smem[rb1 + 0]};                        \
        y[P]     = (v2f){smem[rb0 + 1], smem[rb1 + 1]};                        \
        psi[P]   = (v2f){smem[rb0 + 2], smem[rb1 + 2]};                        \
        v[P]     = (v2f){fmaxf(smem[rb0 + 3], 0.0f),                           \
                         fmaxf(smem[rb1 + 3], 0.0f)};                          \
        a[P]     = (v2f){smem[rb0 + 4], smem[rb1 + 4]};                        \
        delta[P] = (v2f){med3(smem[rb0 + 5], -MAX_STEER, MAX_STEER),           \
                         med3(smem[rb1 + 5], -MAX_STEER, MAX_STEER)};          \
        beta[P]  = (v2f){smem[rb0 + 6], smem[rb1 + 6]};                        \
        r[P]     = (v2f){smem[rb0 + 7], smem[rb1 + 7]};                        \
        a_ref[P] = (v2f){med3(ACT0.x, -6.0f, 3.0f),                            \
                         med3(ACT1.x, -6.0f, 3.0f)};                           \
        d_ref[P] = (v2f){med3(ACT0.y, -MAX_STEER, MAX_STEER),                  \
                         med3(ACT1.y, -MAX_STEER, MAX_STEER)};                 \
        float s0_, c0_, s1_, c1_;                                              \
        __sincosf(psi[P].x + beta[P].x, &s0_, &c0_);                           \
        __sincosf(psi[P].y + beta[P].y, &s1_, &c1_);                           \
        cs[P] = (v2f){c0_, c1_};                                               \
        sn[P] = (v2f){s0_, s1_};                                               \
    } while (0)

#define WRITE_CHAIN(P) do {                                                    \
        const int rb0 = tid * 9;                                               \
        const int rb1 = (tid + 256) * 9;                                       \
        smem[rb0 + 0] = x[P].x;     smem[rb1 + 0] = x[P].y;                    \
        smem[rb0 + 1] = y[P].x;     smem[rb1 + 1] = y[P].y;                    \
        smem[rb0 + 2] = psi[P].x;   smem[rb1 + 2] = psi[P].y;                  \
        smem[rb0 + 3] = v[P].x;     smem[rb1 + 3] = v[P].y;                    \
        smem[rb0 + 4] = a[P].x;     smem[rb1 + 4] = a[P].y;                    \
        smem[rb0 + 5] = delta[P].x; smem[rb1 + 5] = delta[P].y;                \
        smem[rb0 + 6] = beta[P].x;  smem[rb1 + 6] = beta[P].y;                 \
        smem[rb0 + 7] = r[P].x;     smem[rb1 + 7] = r[P].y;                    \
        smem[rb0 + 8] = d_ref[P].x; smem[rb1 + 8] = d_ref[P].y;                \
    } while (0)

#define STORE_HALF(OPTR) do {                                                  \
        f4* o4_ = (f4*)(OPTR);                                                 \
        _Pragma("unroll")                                                      \
        for (int i = 0; i < 4; ++i)                                            \
            __builtin_nontemporal_store(l4[tid + 256 * i], &o4_[tid + 256 * i]); \
        if (tid < 128)                                                         \
            __builtin_nontemporal_store(l4[tid + 1024], &o4_[tid + 1024]);     \
    } while (0)

    READ_CHAIN(0, act[0], act[1]);
    __syncthreads();                       // half-A LDS reads complete
    // ---- stage half B (regs already loaded at entry) ----
#pragma unroll
    for (int i = 0; i < 4; ++i) l4[tid + 256 * i] = rB[i];
    if (tid < 128) l4[tid + 1024] = rB4;
    __syncthreads();
    READ_CHAIN(1, act[2], act[3]);

    // ---- integrate: 10 substeps, 2 independent packed chains ----
#pragma unroll
    for (int k = 0; k < 10; ++k) {
#pragma unroll
        for (int p = 0; p < 2; ++p) {
            v2f v_eff = {fmaxf(v[p].x, V_EFF_MIN), fmaxf(v[p].y, V_EFF_MIN)};
            v2f inv_v = {__builtin_amdgcn_rcpf(v_eff.x), __builtin_amdgcn_rcpf(v_eff.y)};
            v2f t = r[p] * inv_v;
            v2f alpha_f = vfma2((v2f)(1.2f), t, beta[p]) - delta[p];
            v2f alpha_r = vfma2((v2f)(-1.6f), t, beta[p]);
            v2f Ff_raw = alpha_f * -80000.0f;
            v2f Fr_raw = alpha_r * -80000.0f;
            v2f F_yf = {med3(Ff_raw.x, -FY_F_MAX, FY_F_MAX), med3(Ff_raw.y, -FY_F_MAX, FY_F_MAX)};
            v2f F_yr = {med3(Fr_raw.x, -FY_R_MAX, FY_R_MAX), med3(Fr_raw.y, -FY_R_MAX, FY_R_MAX)};
            v2f beta_dot = vfma2(F_yf + F_yr, inv_v * (1.0f / 1500.0f), -r[p]);
            v2f r_dot = vfma2((v2f)(1.2f), F_yf, F_yr * -1.6f) * (1.0f / 2250.0f);

            v2f vh = v[p] * 0.01f;
            x[p] = vfma2(vh, cs[p], x[p]);
            y[p] = vfma2(vh, sn[p], y[p]);

            // incremental heading rotation by d = (r + beta_dot)*h
            v2f d  = (r[p] + beta_dot) * 0.01f;
            v2f cd = vfma2(d * d, (v2f)(-0.5f), (v2f)(1.0f));
            v2f cs_n = vfma2(cs[p], cd, -(sn[p] * d));
            v2f sn_n = vfma2(sn[p], cd, cs[p] * d);

            v2f v_new = vfma2(a[p], (v2f)(0.01f), v[p]);
            v_new = (v2f){fmaxf(v_new.x, 0.0f), fmaxf(v_new.y, 0.0f)};
            psi[p]  = vfma2(r[p], (v2f)(0.01f), psi[p]);
            a[p]    = vfma2(a_ref[p] - a[p], (v2f)(0.1f), a[p]);
            v2f dlt = vfma2(d_ref[p] - delta[p], (v2f)(0.1f), delta[p]);
            delta[p] = (v2f){med3(dlt.x, -MAX_STEER, MAX_STEER), med3(dlt.y, -MAX_STEER, MAX_STEER)};
            beta[p] = vfma2(beta_dot, (v2f)(0.01f), beta[p]);
            r[p]    = vfma2(r_dot, (v2f)(0.01f), r[p]);
            v[p] = v_new;
            cs[p] = cs_n;
            sn[p] = sn_n;
        }
    }

    // ---- epilogue: two half-stores through the same LDS buffer ----
    WRITE_CHAIN(0);                        // self-owned rows, no barrier needed
    __syncthreads();                       // all chain-0 rows written
    STORE_HALF(out + rowBase * 9);
    __syncthreads();                       // store-source ds_reads complete
    WRITE_CHAIN(1);
    __syncthreads();
    STORE_HALF(out + (rowBase + 512) * 9);

#undef READ_CHAIN
#undef WRITE_CHAIN
#undef STORE_HALF
}

extern "C" void kernel_launch(void* const* d_in, const int* in_sizes, int n_in,
                              void* d_out, int out_size, void* d_ws, size_t ws_size,
                              hipStream_t stream) {
    const float* state  = (const float*)d_in[0];
    const float* action = (const float*)d_in[1];
    float* out = (float*)d_out;
    const int rows = in_sizes[0] / 9;        // 4194304
    const int grid = rows / 1024;            // 4096 blocks, exact
    bicycle_kernel<<<grid, 256, 0, stream>>>(state, action, out);
}